// Round 7
// baseline (447.083 us; speedup 1.0000x reference)
//
#include <hip/hip_runtime.h>

constexpr int T = 168;
constexpr int P = 16;
constexpr int H = 24;

typedef float v2f __attribute__((ext_vector_type(2)));

__device__ __forceinline__ v2f mk2(float a, float b) { v2f r; r[0] = a; r[1] = b; return r; }
__device__ __forceinline__ v2f bc2(float a)          { v2f r; r[0] = a; r[1] = a; return r; }
// 2 fp32 FMAs in one instruction (v_pk_fma_f32).
__device__ __forceinline__ v2f pkfma(v2f a, v2f b, v2f c) {
    return __builtin_elementwise_fma(a, b, c);
}

__device__ __forceinline__ float rcp_f(float x) { return __builtin_amdgcn_rcpf(x); }
__device__ __forceinline__ float sigm_f(float x) { return rcp_f(1.f + __expf(-x)); }
// tanh(x) = 2*sigmoid(2x) - 1
__device__ __forceinline__ float tanh_fast(float x) {
    return fmaf(2.f, rcp_f(1.f + __expf(-2.f * x)), -1.f);
}

#define KEEP2(v) asm volatile("" : "+v"(v))
// Intra-wave LDS write->read ordering + compiler reorder fence.
#define LDS_SYNC() asm volatile("s_waitcnt lgkmcnt(0)" ::: "memory")

// 4 packed FMAs: acc += v4.{x,y,z,w} * w[b..b+3]
#define PK4(acc_, v4_, w_, b_) do {                       \
    acc_ = pkfma(bc2((v4_).x), (w_)[(b_)],     acc_);     \
    acc_ = pkfma(bc2((v4_).y), (w_)[(b_) + 1], acc_);     \
    acc_ = pkfma(bc2((v4_).z), (w_)[(b_) + 2], acc_);     \
    acc_ = pkfma(bc2((v4_).w), (w_)[(b_) + 3], acc_); } while (0)

// Gate nonlinearity + state update + h store. tdst==nullptr folds away.
__device__ __forceinline__ void act_store(v2f g, int lane, int half,
                                          float& c, float* hdst, float* tdst)
{
    float a0 = sigm_f(g[0]);                        // i (half0) | f (half1)
    float px = (half == 0) ? g[1] + g[1] : g[1];
    float sv = sigm_f(px);
    float a1 = (half == 0) ? sv + sv - 1.f : sv;    // tanh(g) | o
    float fa = __shfl(a0, lane + 24);
    float oa = __shfl(a1, lane + 24);
    c = fmaf(fa, c, a0 * a1);
    float hv = oa * tanh_fast(c);
    if (tdst) {
        float th = tanh_fast(hv);
        if (lane < H) { hdst[lane] = hv; tdst[lane] = th; }
    } else {
        if (lane < H) hdst[lane] = hv;
    }
}

// R13: R12's wave-specialized split measured best (441us, occ 41.5%, VALU 54%)
// but the allocator REFUSED the 128-reg budget: VGPR_Count=64, WRITE_SIZE
// 34.1MB = ~32 dwords/lane one-time scratch spill of the weight array,
// re-read from L2 every step. Suspected cause: duplicated divergent init
// (two full weight-load bodies + temps feeding 48 KEEP2-pinned v2f) pushed
// peak pressure past 128, so the allocator gave up and optimized occupancy.
// Fix: UNIFORM init — per-wave base-pointer select (Wi/Wh/bi/bh) + runtime
// column count nin (16|24); w[0..23]=input pairs (zero-pad for wave0),
// w[24..47]=recurrent pairs. One init body, one temp set, identical reg
// mapping both waves. Loop-body peak ~122 <= 128. Everything else identical
// to R12: wave0=L1, wave1=L2, t1 double-buffer in LDS, ONE lgkmcnt(0)+
// s_barrier per step, 2048 blocks x 2 waves = 4 waves/SIMD of two DIFFERENT
// instruction streams.
__global__ __attribute__((amdgpu_flat_work_group_size(128, 128),
                          amdgpu_waves_per_eu(4, 4)))
void lstm2_split2(const float* __restrict__ x,
                  const float* __restrict__ Wih1, const float* __restrict__ Whh1,
                  const float* __restrict__ bih1, const float* __restrict__ bhh1,
                  const float* __restrict__ Wih2, const float* __restrict__ Whh2,
                  const float* __restrict__ bih2, const float* __restrict__ bhh2,
                  const float* __restrict__ W1, const float* __restrict__ b1,
                  const float* __restrict__ W2, const float* __restrict__ b2,
                  float* __restrict__ out)
{
    const int tid  = threadIdx.x;
    const int wid  = tid >> 6;                    // 0: L1 wave, 1: L2 wave
    const int lane = tid & 63;
    const int s    = (lane < 48) ? lane : 47;     // clamp idle lanes
    const int u    = s % H;                       // unit 0..23
    const int half = s / H;                       // 0: {i,g}, 1: {f,o}
    const int q0   = half * H + u;                // i or f gate row
    const int q1   = (2 + half) * H + u;          // g or o gate row
    const int rowA = blockIdx.x * 2;
    const int rowB = rowA + 1;

    // ---- uniform weight init: 48 v2f = 96 VGPRs, same mapping both waves --
    // w[0..23]:  input-weight pairs {q0,q1} (cols >= nin zero-padded)
    // w[24..47]: recurrent pairs {q0,q1}
    const float* __restrict__ Wi = wid ? Wih2 : Wih1;
    const float* __restrict__ Wh = wid ? Whh2 : Whh1;
    const float* __restrict__ bi = wid ? bih2 : bih1;
    const float* __restrict__ bh = wid ? bhh2 : bhh1;
    const int nin = wid ? H : P;                  // 24 | 16 (wave-uniform)

    v2f w[48];
    #pragma unroll
    for (int k = 0; k < H; ++k)
        w[k] = (k < nin) ? mk2(Wi[q0 * nin + k], Wi[q1 * nin + k]) : bc2(0.f);
    #pragma unroll
    for (int k = 0; k < H; ++k)
        w[H + k] = mk2(Wh[q0 * H + k], Wh[q1 * H + k]);
    v2f bias = mk2(bi[q0] + bh[q0], bi[q1] + bh[q1]);

    #pragma unroll
    for (int k = 0; k < 48; ++k) KEEP2(w[k]);
    KEEP2(bias);

    __shared__ __align__(16) float h1s[2][32];       // L1 h (wave0-private)
    __shared__ __align__(16) float t1s[2][2][32];    // [buf][row] tanh(h1)
    __shared__ __align__(16) float h2s[2][32];       // L2 h (wave1-private)

    const float* __restrict__ xA = x + (size_t)rowA * T * P;  // wave-uniform
    const float* __restrict__ xB = x + (size_t)rowB * T * P;

    float cA = 0.f, cB = 0.f;     // c1 (wave0) / c2 (wave1)

    // ---- superstep 0: wave0 = L1 step 0 (h1=0 -> x-part only);
    //      wave1 zero-inits h2. h1s/t1s written before first read. ----
    if (wid == 0) {
        v2f gA = bias, gB = bias;
        #pragma unroll
        for (int j = 0; j < P / 4; ++j) {
            float4 va = ((const float4*)xA)[j];
            float4 vb = ((const float4*)xB)[j];
            PK4(gA, va, w, 4 * j);
            PK4(gB, vb, w, 4 * j);
        }
        act_store(gA, lane, half, cA, h1s[0], t1s[0][0]);
        act_store(gB, lane, half, cB, h1s[1], t1s[0][1]);
    } else {
        if (lane < H) { h2s[0][lane] = 0.f; h2s[1][lane] = 0.f; }
    }
    LDS_SYNC();
    __builtin_amdgcn_s_barrier();

    // ---- supersteps 1..T-1: wave0 = L1 step t, wave1 = L2 step t-1 ----
    for (int t = 1; t < T; ++t) {
        if (wid == 0) {
            v2f gA = bias, gB = bias;
            const float4* xa4 = (const float4*)(xA + t * P);
            const float4* xb4 = (const float4*)(xB + t * P);
            #pragma unroll
            for (int j = 0; j < P / 4; ++j) {
                float4 va = xa4[j];
                float4 vb = xb4[j];
                PK4(gA, va, w, 4 * j);
                PK4(gB, vb, w, 4 * j);
            }
            #pragma unroll
            for (int k = 0; k < H / 4; ++k) {
                float4 ha = ((const float4*)h1s[0])[k];
                float4 hb = ((const float4*)h1s[1])[k];
                PK4(gA, ha, w, H + 4 * k);
                PK4(gB, hb, w, H + 4 * k);
            }
            act_store(gA, lane, half, cA, h1s[0], t1s[t & 1][0]);
            act_store(gB, lane, half, cB, h1s[1], t1s[t & 1][1]);
        } else {
            v2f fA = bias, fB = bias;
            const float* t1a = t1s[(t - 1) & 1][0];
            const float* t1b = t1s[(t - 1) & 1][1];
            #pragma unroll
            for (int k = 0; k < H / 4; ++k) {
                float4 ta  = ((const float4*)t1a)[k];
                float4 tb4 = ((const float4*)t1b)[k];
                PK4(fA, ta,  w, 4 * k);
                PK4(fB, tb4, w, 4 * k);
            }
            #pragma unroll
            for (int k = 0; k < H / 4; ++k) {
                float4 ha = ((const float4*)h2s[0])[k];
                float4 hb = ((const float4*)h2s[1])[k];
                PK4(fA, ha, w, H + 4 * k);
                PK4(fB, hb, w, H + 4 * k);
            }
            act_store(fA, lane, half, cA, h2s[0], nullptr);
            act_store(fB, lane, half, cB, h2s[1], nullptr);
        }
        LDS_SYNC();
        __builtin_amdgcn_s_barrier();
    }

    // ---- tail (wave1 only): L2 step T-1, then the head ----
    if (wid == 1) {
        v2f fA = bias, fB = bias;
        const float* t1a = t1s[(T - 1) & 1][0];
        const float* t1b = t1s[(T - 1) & 1][1];
        #pragma unroll
        for (int k = 0; k < H / 4; ++k) {
            float4 ta  = ((const float4*)t1a)[k];
            float4 tb4 = ((const float4*)t1b)[k];
            PK4(fA, ta,  w, 4 * k);
            PK4(fB, tb4, w, 4 * k);
        }
        #pragma unroll
        for (int k = 0; k < H / 4; ++k) {
            float4 ha = ((const float4*)h2s[0])[k];
            float4 hb = ((const float4*)h2s[1])[k];
            PK4(fA, ha, w, H + 4 * k);
            PK4(fB, hb, w, H + 4 * k);
        }
        act_store(fA, lane, half, cA, h2s[0], nullptr);
        act_store(fB, lane, half, cB, h2s[1], nullptr);
        LDS_SYNC();

        // head: tanh -> fc1(16, relu) -> fc2(24), both rows (intra-wave)
        if (lane < H) {
            t1s[0][0][lane] = tanh_fast(h2s[0][lane]);
            t1s[0][1][lane] = tanh_fast(h2s[1][lane]);
        }
        LDS_SYNC();
        if (lane < 16) {
            float accA = b1[lane], accB = b1[lane];
            #pragma unroll
            for (int j = 0; j < H; ++j) {
                float wv = W1[lane * H + j];
                accA = fmaf(t1s[0][0][j], wv, accA);
                accB = fmaf(t1s[0][1][j], wv, accB);
            }
            h1s[0][lane] = fmaxf(accA, 0.f);
            h1s[1][lane] = fmaxf(accB, 0.f);
        }
        LDS_SYNC();
        if (lane < H) {
            float accA = b2[lane], accB = b2[lane];
            #pragma unroll
            for (int j = 0; j < 16; ++j) {
                float wv = W2[lane * 16 + j];
                accA = fmaf(h1s[0][j], wv, accA);
                accB = fmaf(h1s[1][j], wv, accB);
            }
            out[(size_t)rowA * H + lane] = accA;
            out[(size_t)rowB * H + lane] = accB;
        }
    }
}

extern "C" void kernel_launch(void* const* d_in, const int* in_sizes, int n_in,
                              void* d_out, int out_size, void* d_ws, size_t ws_size,
                              hipStream_t stream)
{
    const float* x    = (const float*)d_in[0];
    const float* Wih1 = (const float*)d_in[1];
    const float* Whh1 = (const float*)d_in[2];
    const float* bih1 = (const float*)d_in[3];
    const float* bhh1 = (const float*)d_in[4];
    const float* Wih2 = (const float*)d_in[5];
    const float* Whh2 = (const float*)d_in[6];
    const float* bih2 = (const float*)d_in[7];
    const float* bhh2 = (const float*)d_in[8];
    const float* W1   = (const float*)d_in[9];
    const float* b1   = (const float*)d_in[10];
    const float* W2   = (const float*)d_in[11];
    const float* b2   = (const float*)d_in[12];
    float* out = (float*)d_out;

    const int B = in_sizes[0] / (T * P);             // 4096
    hipLaunchKernelGGL(lstm2_split2, dim3(B / 2), dim3(128), 0, stream,
                       x, Wih1, Whh1, bih1, bhh1, Wih2, Whh2, bih2, bhh2,
                       W1, b1, W2, b2, out);
}

// Round 8
// 365.322 us; speedup vs baseline: 1.2238x; 1.2238x over previous
//
#include <hip/hip_runtime.h>

constexpr int T = 168;
constexpr int P = 16;
constexpr int H = 24;

typedef float v2f __attribute__((ext_vector_type(2)));

__device__ __forceinline__ v2f mk2(float a, float b) { v2f r; r[0] = a; r[1] = b; return r; }
__device__ __forceinline__ v2f bc2(float a)          { v2f r; r[0] = a; r[1] = a; return r; }
// 2 fp32 FMAs in one instruction (v_pk_fma_f32).
__device__ __forceinline__ v2f pkfma(v2f a, v2f b, v2f c) {
    return __builtin_elementwise_fma(a, b, c);
}

__device__ __forceinline__ float rcp_f(float x) { return __builtin_amdgcn_rcpf(x); }
__device__ __forceinline__ float sigm_f(float x) { return rcp_f(1.f + __expf(-x)); }
// tanh(x) = 2*sigmoid(2x) - 1
__device__ __forceinline__ float tanh_fast(float x) {
    return fmaf(2.f, rcp_f(1.f + __expf(-2.f * x)), -1.f);
}

#define KEEP2(v) asm volatile("" : "+v"(v))
// Intra-wave LDS write->read ordering + compiler reorder fence.
#define LDS_SYNC() asm volatile("s_waitcnt lgkmcnt(0)" ::: "memory")

// 4 packed FMAs: acc += v4.{x,y,z,w} * w[b..b+3]
#define PK4(acc_, v4_, w_, b_) do {                       \
    acc_ = pkfma(bc2((v4_).x), (w_)[(b_)],     acc_);     \
    acc_ = pkfma(bc2((v4_).y), (w_)[(b_) + 1], acc_);     \
    acc_ = pkfma(bc2((v4_).z), (w_)[(b_) + 2], acc_);     \
    acc_ = pkfma(bc2((v4_).w), (w_)[(b_) + 3], acc_); } while (0)

// Gate nonlinearity + state update + h store. tdst==nullptr folds away.
__device__ __forceinline__ void act_store(v2f g, int lane, int half,
                                          float& c, float* hdst, float* tdst)
{
    float a0 = sigm_f(g[0]);                        // i (half0) | f (half1)
    float px = (half == 0) ? g[1] + g[1] : g[1];
    float sv = sigm_f(px);
    float a1 = (half == 0) ? sv + sv - 1.f : sv;    // tanh(g) | o
    float fa = __shfl(a0, lane + 24);
    float oa = __shfl(a1, lane + 24);
    c = fmaf(fa, c, a0 * a1);
    float hv = oa * tanh_fast(c);
    if (tdst) {
        float th = tanh_fast(hv);
        if (lane < H) { hdst[lane] = hv; tdst[lane] = th; }
    } else {
        if (lane < H) hdst[lane] = hv;
    }
}

// R14: R12/R13 proved the wave-specialized split (occ 41.5%, best 413us
// steady) but the allocator settled at the 64-reg/8-wave tier under
// waves_per_eu(4,4), spilling 16 v2f of weights to scratch (WRITE 34.9MB =
// ~33 dwords/lane one-time; kept 32 v2f = the reported VGPR_Count=64), and
// the per-step L2 reload latency is the remaining ~47% no-issue.
// Fix 1: amdgpu_num_vgpr(128) — explicitly grant the 4-waves/SIMD register
// tier; the allocator can no longer trade registers for occupancy.
// Fix 2: shave true peak demand to ~120: rows A and B run SEQUENTIALLY in
// each phase (one live float4 instead of four). Per-wave ILP drops; the 4
// resident waves/SIMD of two DIFFERENT instruction streams cover stalls.
// Everything else identical to R13: wave0=L1, wave1=L2, t1 double-buffer,
// ONE lgkmcnt(0)+s_barrier per superstep, 2048 blocks x 2 waves.
__global__ __attribute__((amdgpu_flat_work_group_size(128, 128),
                          amdgpu_num_vgpr(128)))
void lstm2_split3(const float* __restrict__ x,
                  const float* __restrict__ Wih1, const float* __restrict__ Whh1,
                  const float* __restrict__ bih1, const float* __restrict__ bhh1,
                  const float* __restrict__ Wih2, const float* __restrict__ Whh2,
                  const float* __restrict__ bih2, const float* __restrict__ bhh2,
                  const float* __restrict__ W1, const float* __restrict__ b1,
                  const float* __restrict__ W2, const float* __restrict__ b2,
                  float* __restrict__ out)
{
    const int tid  = threadIdx.x;
    const int wid  = tid >> 6;                    // 0: L1 wave, 1: L2 wave
    const int lane = tid & 63;
    const int s    = (lane < 48) ? lane : 47;     // clamp idle lanes
    const int u    = s % H;                       // unit 0..23
    const int half = s / H;                       // 0: {i,g}, 1: {f,o}
    const int q0   = half * H + u;                // i or f gate row
    const int q1   = (2 + half) * H + u;          // g or o gate row
    const int rowA = blockIdx.x * 2;
    const int rowB = rowA + 1;

    // ---- uniform weight init: 48 v2f = 96 VGPRs, same mapping both waves --
    // w[0..23]:  input-weight pairs {q0,q1} (cols >= nin zero-padded)
    // w[24..47]: recurrent pairs {q0,q1}
    const float* __restrict__ Wi = wid ? Wih2 : Wih1;
    const float* __restrict__ Wh = wid ? Whh2 : Whh1;
    const float* __restrict__ bi = wid ? bih2 : bih1;
    const float* __restrict__ bh = wid ? bhh2 : bhh1;
    const int nin = wid ? H : P;                  // 24 | 16 (wave-uniform)

    v2f w[48];
    #pragma unroll
    for (int k = 0; k < H; ++k)
        w[k] = (k < nin) ? mk2(Wi[q0 * nin + k], Wi[q1 * nin + k]) : bc2(0.f);
    #pragma unroll
    for (int k = 0; k < H; ++k)
        w[H + k] = mk2(Wh[q0 * H + k], Wh[q1 * H + k]);
    v2f bias = mk2(bi[q0] + bh[q0], bi[q1] + bh[q1]);

    #pragma unroll
    for (int k = 0; k < 48; ++k) KEEP2(w[k]);
    KEEP2(bias);

    __shared__ __align__(16) float h1s[2][32];       // L1 h (wave0-private)
    __shared__ __align__(16) float t1s[2][2][32];    // [buf][row] tanh(h1)
    __shared__ __align__(16) float h2s[2][32];       // L2 h (wave1-private)

    const float* __restrict__ xA = x + (size_t)rowA * T * P;  // wave-uniform
    const float* __restrict__ xB = x + (size_t)rowB * T * P;

    float cA = 0.f, cB = 0.f;     // c1 (wave0) / c2 (wave1)

    // ---- superstep 0: wave0 = L1 step 0 (h1=0 -> x-part only);
    //      wave1 zero-inits h2. h1s/t1s written before first read. ----
    if (wid == 0) {
        v2f gA = bias;
        #pragma unroll
        for (int j = 0; j < P / 4; ++j) {
            float4 va = ((const float4*)xA)[j];
            PK4(gA, va, w, 4 * j);
        }
        act_store(gA, lane, half, cA, h1s[0], t1s[0][0]);
        v2f gB = bias;
        #pragma unroll
        for (int j = 0; j < P / 4; ++j) {
            float4 vb = ((const float4*)xB)[j];
            PK4(gB, vb, w, 4 * j);
        }
        act_store(gB, lane, half, cB, h1s[1], t1s[0][1]);
    } else {
        if (lane < H) { h2s[0][lane] = 0.f; h2s[1][lane] = 0.f; }
    }
    LDS_SYNC();
    __builtin_amdgcn_s_barrier();

    // ---- supersteps 1..T-1: wave0 = L1 step t, wave1 = L2 step t-1 ----
    for (int t = 1; t < T; ++t) {
        if (wid == 0) {
            // ---- row A fully, then row B (one float4 staging slot live) ----
            v2f gA = bias;
            {
                const float4* xa4 = (const float4*)(xA + t * P);
                #pragma unroll
                for (int j = 0; j < P / 4; ++j) {
                    float4 va = xa4[j];
                    PK4(gA, va, w, 4 * j);
                }
                #pragma unroll
                for (int k = 0; k < H / 4; ++k) {
                    float4 ha = ((const float4*)h1s[0])[k];
                    PK4(gA, ha, w, H + 4 * k);
                }
            }
            act_store(gA, lane, half, cA, h1s[0], t1s[t & 1][0]);
            v2f gB = bias;
            {
                const float4* xb4 = (const float4*)(xB + t * P);
                #pragma unroll
                for (int j = 0; j < P / 4; ++j) {
                    float4 vb = xb4[j];
                    PK4(gB, vb, w, 4 * j);
                }
                #pragma unroll
                for (int k = 0; k < H / 4; ++k) {
                    float4 hb = ((const float4*)h1s[1])[k];
                    PK4(gB, hb, w, H + 4 * k);
                }
            }
            act_store(gB, lane, half, cB, h1s[1], t1s[t & 1][1]);
        } else {
            v2f fA = bias;
            {
                const float* t1a = t1s[(t - 1) & 1][0];
                #pragma unroll
                for (int k = 0; k < H / 4; ++k) {
                    float4 ta = ((const float4*)t1a)[k];
                    PK4(fA, ta, w, 4 * k);
                }
                #pragma unroll
                for (int k = 0; k < H / 4; ++k) {
                    float4 ha = ((const float4*)h2s[0])[k];
                    PK4(fA, ha, w, H + 4 * k);
                }
            }
            act_store(fA, lane, half, cA, h2s[0], nullptr);
            v2f fB = bias;
            {
                const float* t1b = t1s[(t - 1) & 1][1];
                #pragma unroll
                for (int k = 0; k < H / 4; ++k) {
                    float4 tb4 = ((const float4*)t1b)[k];
                    PK4(fB, tb4, w, 4 * k);
                }
                #pragma unroll
                for (int k = 0; k < H / 4; ++k) {
                    float4 hb = ((const float4*)h2s[1])[k];
                    PK4(fB, hb, w, H + 4 * k);
                }
            }
            act_store(fB, lane, half, cB, h2s[1], nullptr);
        }
        LDS_SYNC();
        __builtin_amdgcn_s_barrier();
    }

    // ---- tail (wave1 only): L2 step T-1, then the head ----
    if (wid == 1) {
        v2f fA = bias;
        {
            const float* t1a = t1s[(T - 1) & 1][0];
            #pragma unroll
            for (int k = 0; k < H / 4; ++k) {
                float4 ta = ((const float4*)t1a)[k];
                PK4(fA, ta, w, 4 * k);
            }
            #pragma unroll
            for (int k = 0; k < H / 4; ++k) {
                float4 ha = ((const float4*)h2s[0])[k];
                PK4(fA, ha, w, H + 4 * k);
            }
        }
        act_store(fA, lane, half, cA, h2s[0], nullptr);
        v2f fB = bias;
        {
            const float* t1b = t1s[(T - 1) & 1][1];
            #pragma unroll
            for (int k = 0; k < H / 4; ++k) {
                float4 tb4 = ((const float4*)t1b)[k];
                PK4(fB, tb4, w, 4 * k);
            }
            #pragma unroll
            for (int k = 0; k < H / 4; ++k) {
                float4 hb = ((const float4*)h2s[1])[k];
                PK4(fB, hb, w, H + 4 * k);
            }
        }
        act_store(fB, lane, half, cB, h2s[1], nullptr);
        LDS_SYNC();

        // head: tanh -> fc1(16, relu) -> fc2(24), both rows (intra-wave)
        if (lane < H) {
            t1s[0][0][lane] = tanh_fast(h2s[0][lane]);
            t1s[0][1][lane] = tanh_fast(h2s[1][lane]);
        }
        LDS_SYNC();
        if (lane < 16) {
            float accA = b1[lane], accB = b1[lane];
            #pragma unroll
            for (int j = 0; j < H; ++j) {
                float wv = W1[lane * H + j];
                accA = fmaf(t1s[0][0][j], wv, accA);
                accB = fmaf(t1s[0][1][j], wv, accB);
            }
            h1s[0][lane] = fmaxf(accA, 0.f);
            h1s[1][lane] = fmaxf(accB, 0.f);
        }
        LDS_SYNC();
        if (lane < H) {
            float accA = b2[lane], accB = b2[lane];
            #pragma unroll
            for (int j = 0; j < 16; ++j) {
                float wv = W2[lane * 16 + j];
                accA = fmaf(h1s[0][j], wv, accA);
                accB = fmaf(h1s[1][j], wv, accB);
            }
            out[(size_t)rowA * H + lane] = accA;
            out[(size_t)rowB * H + lane] = accB;
        }
    }
}

extern "C" void kernel_launch(void* const* d_in, const int* in_sizes, int n_in,
                              void* d_out, int out_size, void* d_ws, size_t ws_size,
                              hipStream_t stream)
{
    const float* x    = (const float*)d_in[0];
    const float* Wih1 = (const float*)d_in[1];
    const float* Whh1 = (const float*)d_in[2];
    const float* bih1 = (const float*)d_in[3];
    const float* bhh1 = (const float*)d_in[4];
    const float* Wih2 = (const float*)d_in[5];
    const float* Whh2 = (const float*)d_in[6];
    const float* bih2 = (const float*)d_in[7];
    const float* bhh2 = (const float*)d_in[8];
    const float* W1   = (const float*)d_in[9];
    const float* b1   = (const float*)d_in[10];
    const float* W2   = (const float*)d_in[11];
    const float* b2   = (const float*)d_in[12];
    float* out = (float*)d_out;

    const int B = in_sizes[0] / (T * P);             // 4096
    hipLaunchKernelGGL(lstm2_split3, dim3(B / 2), dim3(128), 0, stream,
                       x, Wih1, Whh1, bih1, bhh1, Wih2, Whh2, bih2, bhh2,
                       W1, b1, W2, b2, out);
}

// Round 10
// 360.182 us; speedup vs baseline: 1.2413x; 1.0143x over previous
//
#include <hip/hip_runtime.h>

constexpr int T = 168;
constexpr int P = 16;
constexpr int H = 24;

typedef float v2f __attribute__((ext_vector_type(2)));

__device__ __forceinline__ v2f mk2(float a, float b) { v2f r; r[0] = a; r[1] = b; return r; }
__device__ __forceinline__ v2f bc2(float a)          { v2f r; r[0] = a; r[1] = a; return r; }
// 2 fp32 FMAs in one instruction (v_pk_fma_f32).
__device__ __forceinline__ v2f pkfma(v2f a, v2f b, v2f c) {
    return __builtin_elementwise_fma(a, b, c);
}

__device__ __forceinline__ float rcp_f(float x) { return __builtin_amdgcn_rcpf(x); }
__device__ __forceinline__ float sigm_f(float x) { return rcp_f(1.f + __expf(-x)); }
// tanh(x) = 2*sigmoid(2x) - 1
__device__ __forceinline__ float tanh_fast(float x) {
    return fmaf(2.f, rcp_f(1.f + __expf(-2.f * x)), -1.f);
}

#define KEEP2(v) asm volatile("" : "+v"(v))
// Intra-wave LDS write->read ordering + compiler reorder fence.
#define LDS_SYNC() asm volatile("s_waitcnt lgkmcnt(0)" ::: "memory")

// 4 packed FMAs: acc += v4.{x,y,z,w} * w[b..b+3]
#define PK4(acc_, v4_, w_, b_) do {                       \
    acc_ = pkfma(bc2((v4_).x), (w_)[(b_)],     acc_);     \
    acc_ = pkfma(bc2((v4_).y), (w_)[(b_) + 1], acc_);     \
    acc_ = pkfma(bc2((v4_).z), (w_)[(b_) + 2], acc_);     \
    acc_ = pkfma(bc2((v4_).w), (w_)[(b_) + 3], acc_); } while (0)

// Gate nonlinearity + state update + h store. tdst==nullptr folds away.
__device__ __forceinline__ void act_store(v2f g, int lane, int half,
                                          float& c, float* hdst, float* tdst)
{
    float a0 = sigm_f(g[0]);                        // i (half0) | f (half1)
    float px = (half == 0) ? g[1] + g[1] : g[1];
    float sv = sigm_f(px);
    float a1 = (half == 0) ? sv + sv - 1.f : sv;    // tanh(g) | o
    float fa = __shfl(a0, lane + 24);
    float oa = __shfl(a1, lane + 24);
    c = fmaf(fa, c, a0 * a1);
    float hv = oa * tanh_fast(c);
    if (tdst) {
        float th = tanh_fast(hv);
        if (lane < H) { hdst[lane] = hv; tdst[lane] = th; }
    } else {
        if (lane < H) hdst[lane] = hv;
    }
}

// One L1 timestep for one row: g = bias + Wih1*x[t] + Whh1*h1; update c,h,t.
#define L1_STEP(xrow_, hrow_, c_, tdst_) do {                          \
    v2f g_ = bias;                                                     \
    const float4* x4_ = (const float4*)(xrow_);                        \
    _Pragma("unroll")                                                  \
    for (int j_ = 0; j_ < P / 4; ++j_) {                               \
        float4 v_ = x4_[j_];                                           \
        PK4(g_, v_, w, 4 * j_);                                        \
    }                                                                  \
    _Pragma("unroll")                                                  \
    for (int k_ = 0; k_ < H / 4; ++k_) {                               \
        float4 hv_ = ((const float4*)(hrow_))[k_];                     \
        PK4(g_, hv_, w, H + 4 * k_);                                   \
    }                                                                  \
    act_store(g_, lane, half, c_, hrow_, tdst_);                       \
} while (0)

// One L2 timestep for one row: f = bias + Wih2*t1 + Whh2*h2; update c,h.
#define L2_STEP(trow_, hrow_, c_) do {                                 \
    v2f f_ = bias;                                                     \
    _Pragma("unroll")                                                  \
    for (int k_ = 0; k_ < H / 4; ++k_) {                               \
        float4 tv_ = ((const float4*)(trow_))[k_];                     \
        PK4(f_, tv_, w, 4 * k_);                                       \
    }                                                                  \
    _Pragma("unroll")                                                  \
    for (int k_ = 0; k_ < H / 4; ++k_) {                               \
        float4 hv_ = ((const float4*)(hrow_))[k_];                     \
        PK4(f_, hv_, w, H + 4 * k_);                                   \
    }                                                                  \
    act_store(f_, lane, half, c_, hrow_, nullptr);                     \
} while (0)

// R15 (resubmit after infra failure): amortize per-step fixed costs — 2
// timesteps per superstep.
// R14 evidence: 337us steady, VALUBusy 63%, zero scratch (VGPR_Count=64 with
// ~96 regs of weights => overflow parked in AGPRs, moves ~3%/superstep =
// negligible). Residual 37% no-issue = per-step fixed costs x168: barrier
// skew (wave0 80 pkfma vs wave1 96), lgkm drain, x first-use stall.
// Change: wave0 owns the whole L1 recurrence -> it runs steps {2s,2s+1}
// back-to-back with only an intra-wave lgkmcnt(0) between (own h1 handoff);
// wave1 likewise runs {2s-2,2s-1}. Barriers 167->84; t1 handoff 2 vectors
// per barrier; x loads batch 2 steps (step-b loads hide under step-a FMAs);
// loop overhead halves. Per-phase register pressure unchanged (one float4 +
// one gate acc live) so the 64+AGPR allocation should reproduce.
// Keeps: wave0=L1/wave1=L2 split, t1 double-buffer (by superstep parity),
// uniform weight init, amdgpu_num_vgpr(128), 2048 blocks x 2 waves.
__global__ __attribute__((amdgpu_flat_work_group_size(128, 128),
                          amdgpu_num_vgpr(128)))
void lstm2_split4(const float* __restrict__ x,
                  const float* __restrict__ Wih1, const float* __restrict__ Whh1,
                  const float* __restrict__ bih1, const float* __restrict__ bhh1,
                  const float* __restrict__ Wih2, const float* __restrict__ Whh2,
                  const float* __restrict__ bih2, const float* __restrict__ bhh2,
                  const float* __restrict__ W1, const float* __restrict__ b1,
                  const float* __restrict__ W2, const float* __restrict__ b2,
                  float* __restrict__ out)
{
    const int tid  = threadIdx.x;
    const int wid  = tid >> 6;                    // 0: L1 wave, 1: L2 wave
    const int lane = tid & 63;
    const int s    = (lane < 48) ? lane : 47;     // clamp idle lanes
    const int u    = s % H;                       // unit 0..23
    const int half = s / H;                       // 0: {i,g}, 1: {f,o}
    const int q0   = half * H + u;                // i or f gate row
    const int q1   = (2 + half) * H + u;          // g or o gate row
    const int rowA = blockIdx.x * 2;
    const int rowB = rowA + 1;

    // ---- uniform weight init: 48 v2f = 96 regs, same mapping both waves ----
    // w[0..23]:  input-weight pairs {q0,q1} (cols >= nin zero-padded)
    // w[24..47]: recurrent pairs {q0,q1}
    const float* __restrict__ Wi = wid ? Wih2 : Wih1;
    const float* __restrict__ Wh = wid ? Whh2 : Whh1;
    const float* __restrict__ bi = wid ? bih2 : bih1;
    const float* __restrict__ bh = wid ? bhh2 : bhh1;
    const int nin = wid ? H : P;                  // 24 | 16 (wave-uniform)

    v2f w[48];
    #pragma unroll
    for (int k = 0; k < H; ++k)
        w[k] = (k < nin) ? mk2(Wi[q0 * nin + k], Wi[q1 * nin + k]) : bc2(0.f);
    #pragma unroll
    for (int k = 0; k < H; ++k)
        w[H + k] = mk2(Wh[q0 * H + k], Wh[q1 * H + k]);
    v2f bias = mk2(bi[q0] + bh[q0], bi[q1] + bh[q1]);

    #pragma unroll
    for (int k = 0; k < 48; ++k) KEEP2(w[k]);
    KEEP2(bias);

    __shared__ __align__(16) float h1s[2][32];          // L1 h (wave0-private)
    __shared__ __align__(16) float t1s[2][2][2][32];    // [buf][step][row]
    __shared__ __align__(16) float h2s[2][32];          // L2 h (wave1-private)

    const float* __restrict__ xA = x + (size_t)rowA * T * P;  // wave-uniform
    const float* __restrict__ xB = x + (size_t)rowB * T * P;

    float cA = 0.f, cB = 0.f;     // c1 (wave0) / c2 (wave1)

    // ---- superstep 0: wave0 = L1 steps {0,1}; wave1 zero-inits h2 ----
    if (wid == 0) {
        // step 0: h1 = 0 -> x-part only
        {
            v2f g = bias;
            #pragma unroll
            for (int j = 0; j < P / 4; ++j) {
                float4 v = ((const float4*)xA)[j];
                PK4(g, v, w, 4 * j);
            }
            act_store(g, lane, half, cA, h1s[0], t1s[0][0][0]);
        }
        {
            v2f g = bias;
            #pragma unroll
            for (int j = 0; j < P / 4; ++j) {
                float4 v = ((const float4*)xB)[j];
                PK4(g, v, w, 4 * j);
            }
            act_store(g, lane, half, cB, h1s[1], t1s[0][0][1]);
        }
        LDS_SYNC();                     // own h1 writes -> own reads
        // step 1: full
        L1_STEP(xA + P, h1s[0], cA, t1s[0][1][0]);
        L1_STEP(xB + P, h1s[1], cB, t1s[0][1][1]);
    } else {
        if (lane < H) { h2s[0][lane] = 0.f; h2s[1][lane] = 0.f; }
    }
    LDS_SYNC();
    __builtin_amdgcn_s_barrier();

    // ---- supersteps 1..83: wave0 = L1 {2s,2s+1}; wave1 = L2 {2s-2,2s-1} ----
    for (int ss = 1; ss < T / 2; ++ss) {
        if (wid == 0) {
            const int ta = 2 * ss;
            L1_STEP(xA + ta * P,       h1s[0], cA, t1s[ss & 1][0][0]);
            L1_STEP(xB + ta * P,       h1s[1], cB, t1s[ss & 1][0][1]);
            LDS_SYNC();
            L1_STEP(xA + (ta + 1) * P, h1s[0], cA, t1s[ss & 1][1][0]);
            L1_STEP(xB + (ta + 1) * P, h1s[1], cB, t1s[ss & 1][1][1]);
        } else {
            const int pb = (ss - 1) & 1;
            L2_STEP(t1s[pb][0][0], h2s[0], cA);
            L2_STEP(t1s[pb][0][1], h2s[1], cB);
            LDS_SYNC();
            L2_STEP(t1s[pb][1][0], h2s[0], cA);
            L2_STEP(t1s[pb][1][1], h2s[1], cB);
        }
        LDS_SYNC();
        __builtin_amdgcn_s_barrier();
    }

    // ---- tail (wave1 only): L2 steps {166,167} from buf 1, then head ----
    if (wid == 1) {
        L2_STEP(t1s[1][0][0], h2s[0], cA);
        L2_STEP(t1s[1][0][1], h2s[1], cB);
        LDS_SYNC();
        L2_STEP(t1s[1][1][0], h2s[0], cA);
        L2_STEP(t1s[1][1][1], h2s[1], cB);
        LDS_SYNC();

        // head: tanh -> fc1(16, relu) -> fc2(24), both rows (intra-wave)
        if (lane < H) {
            t1s[0][0][0][lane] = tanh_fast(h2s[0][lane]);
            t1s[0][0][1][lane] = tanh_fast(h2s[1][lane]);
        }
        LDS_SYNC();
        if (lane < 16) {
            float accA = b1[lane], accB = b1[lane];
            #pragma unroll
            for (int j = 0; j < H; ++j) {
                float wv = W1[lane * H + j];
                accA = fmaf(t1s[0][0][0][j], wv, accA);
                accB = fmaf(t1s[0][0][1][j], wv, accB);
            }
            h1s[0][lane] = fmaxf(accA, 0.f);
            h1s[1][lane] = fmaxf(accB, 0.f);
        }
        LDS_SYNC();
        if (lane < H) {
            float accA = b2[lane], accB = b2[lane];
            #pragma unroll
            for (int j = 0; j < 16; ++j) {
                float wv = W2[lane * 16 + j];
                accA = fmaf(h1s[0][j], wv, accA);
                accB = fmaf(h1s[1][j], wv, accB);
            }
            out[(size_t)rowA * H + lane] = accA;
            out[(size_t)rowB * H + lane] = accB;
        }
    }
}

extern "C" void kernel_launch(void* const* d_in, const int* in_sizes, int n_in,
                              void* d_out, int out_size, void* d_ws, size_t ws_size,
                              hipStream_t stream)
{
    const float* x    = (const float*)d_in[0];
    const float* Wih1 = (const float*)d_in[1];
    const float* Whh1 = (const float*)d_in[2];
    const float* bih1 = (const float*)d_in[3];
    const float* bhh1 = (const float*)d_in[4];
    const float* Wih2 = (const float*)d_in[5];
    const float* Whh2 = (const float*)d_in[6];
    const float* bih2 = (const float*)d_in[7];
    const float* bhh2 = (const float*)d_in[8];
    const float* W1   = (const float*)d_in[9];
    const float* b1   = (const float*)d_in[10];
    const float* W2   = (const float*)d_in[11];
    const float* b2   = (const float*)d_in[12];
    float* out = (float*)d_out;

    const int B = in_sizes[0] / (T * P);             // 4096
    hipLaunchKernelGGL(lstm2_split4, dim3(B / 2), dim3(128), 0, stream,
                       x, Wih1, Whh1, bih1, bhh1, Wih2, Whh2, bih2, bhh2,
                       W1, b1, W2, b2, out);
}